// Round 1
// baseline (486.031 us; speedup 1.0000x reference)
//
#include <hip/hip_runtime.h>
#include <math.h>

// HyperbolicGRUCell: B=32768, I=H=512, c=0.01 (sqrt_c = 0.1)
// Pipeline:
//   1) scales_kernel : per-row log-map multiplier for x and h (fp32)
//   2) cvt_kernel    : W_ih / W_hh fp32 -> bf16 (ws)
//   3) gru_gemm_kernel: fused dual-GEMM (bf16 MFMA) + GRU gates -> d_out (= h_new_t, fp32)
//   4) expmap_kernel : in-place exp-map on d_out

typedef __attribute__((ext_vector_type(8))) short bf16x8;           // MFMA A/B frag (8 bf16)
typedef __attribute__((ext_vector_type(8))) unsigned short u16x8;   // staging vector
typedef __attribute__((ext_vector_type(4))) float f32x4;            // MFMA C/D frag

__device__ __forceinline__ unsigned short f2bf(float f) {
    // round-to-nearest-even fp32 -> bf16
    unsigned int u = __float_as_uint(f);
    u += 0x7FFFu + ((u >> 16) & 1u);
    return (unsigned short)(u >> 16);
}

__device__ __forceinline__ u16x8 cvt8(float4 v0, float4 v1, float s) {
    u16x8 r;
    r[0] = f2bf(v0.x * s); r[1] = f2bf(v0.y * s); r[2] = f2bf(v0.z * s); r[3] = f2bf(v0.w * s);
    r[4] = f2bf(v1.x * s); r[5] = f2bf(v1.y * s); r[6] = f2bf(v1.z * s); r[7] = f2bf(v1.w * s);
    return r;
}

// ---------------------------------------------------------------------------
// 1) per-row log-map multiplier: m = artanh(0.1*norm) / (0.1*norm)
//    one wave per row; rows [0,B) = x, rows [B,2B) = h
// ---------------------------------------------------------------------------
__global__ void scales_kernel(const float* __restrict__ x, const float* __restrict__ h,
                              float* __restrict__ mx, float* __restrict__ mh,
                              int B, int D) {
    int wave = threadIdx.x >> 6;
    int lane = threadIdx.x & 63;
    int row = blockIdx.x * 4 + wave;            // 0 .. 2B-1
    int r = (row < B) ? row : row - B;
    const float* src = (row < B) ? x : h;
    const float4* p = (const float4*)(src + (size_t)r * D);
    int nv = D >> 2;                            // 128 float4 per row
    float s = 0.f;
    for (int i = lane; i < nv; i += 64) {
        float4 v = p[i];
        s += v.x * v.x + v.y * v.y + v.z * v.z + v.w * v.w;
    }
    #pragma unroll
    for (int off = 32; off; off >>= 1) s += __shfl_xor(s, off);
    float norm = fmaxf(sqrtf(s), 1e-15f);
    float a = fminf(0.1f * norm, 1.f - 1e-5f);  // clip inside artanh only
    float m = 0.5f * (log1pf(a) - log1pf(-a)) / (0.1f * norm);
    if (lane == 0) {
        if (row < B) mx[r] = m; else mh[r] = m;
    }
}

// ---------------------------------------------------------------------------
// 2) weight fp32 -> bf16
// ---------------------------------------------------------------------------
__global__ void cvt_kernel(const float* __restrict__ src, unsigned short* __restrict__ dst, int n4) {
    int i = blockIdx.x * blockDim.x + threadIdx.x;
    if (i < n4) {
        float4 v = ((const float4*)src)[i];
        ushort4 o;
        o.x = f2bf(v.x); o.y = f2bf(v.y); o.z = f2bf(v.z); o.w = f2bf(v.w);
        ((ushort4*)dst)[i] = o;
    }
}

// ---------------------------------------------------------------------------
// 3) fused dual-GEMM + GRU gates. BM=128, BN=32, BK=32, K=512.
//    Gates g=0..2: x_t @ W_ih^T rows {r,z,n};  g=3..5: h_t @ W_hh^T rows {r,z,n}.
//    Each wave: 32 rows x 32 cols x 6 gates -> acc = 6*2*2 f32x4 = 96 VGPR.
//    LDS stride 40 bf16 (80B = odd number of 16B granules -> balanced b128 banks).
// ---------------------------------------------------------------------------
__launch_bounds__(256, 2)
__global__ void gru_gemm_kernel(const float* __restrict__ x, const float* __restrict__ h,
                                const float* __restrict__ mx, const float* __restrict__ mh,
                                const unsigned short* __restrict__ Wih,
                                const unsigned short* __restrict__ Whh,
                                const float* __restrict__ bih, const float* __restrict__ bhh,
                                float* __restrict__ out, int H) {
    const int K = 512;                            // == I == H
    __shared__ unsigned short sAx[128][40];
    __shared__ unsigned short sAh[128][40];
    __shared__ unsigned short sW[6][32][40];

    int t = threadIdx.x;
    int wave = t >> 6, lane = t & 63;
    int quad = lane >> 4, lr = lane & 15;
    int r0 = blockIdx.y * 128;
    int n0 = blockIdx.x * 32;

    f32x4 acc[6][2][2];
    #pragma unroll
    for (int g = 0; g < 6; ++g)
        #pragma unroll
        for (int i = 0; i < 2; ++i)
            #pragma unroll
            for (int j = 0; j < 2; ++j)
                acc[g][i][j] = (f32x4){0.f, 0.f, 0.f, 0.f};

    // staging assignment: thread t stages row (t>>1), 16-col half (t&1)
    int srow = t >> 1;
    int shalf = t & 1;
    float smx = mx[r0 + srow];
    float smh = mh[r0 + srow];
    const float* px = x + (size_t)(r0 + srow) * K + shalf * 16;
    const float* ph = h + (size_t)(r0 + srow) * K + shalf * 16;

    for (int k0 = 0; k0 < K; k0 += 32) {
        __syncthreads();   // protect LDS from previous iteration's readers
        // ---- stage A tiles (fp32 load, log-map scale, bf16 cast) ----
        {
            const float4* p4x = (const float4*)(px + k0);
            float4 x0 = p4x[0], x1 = p4x[1], x2 = p4x[2], x3 = p4x[3];
            const float4* p4h = (const float4*)(ph + k0);
            float4 h0 = p4h[0], h1 = p4h[1], h2 = p4h[2], h3 = p4h[3];
            *(u16x8*)&sAx[srow][shalf * 16]     = cvt8(x0, x1, smx);
            *(u16x8*)&sAx[srow][shalf * 16 + 8] = cvt8(x2, x3, smx);
            *(u16x8*)&sAh[srow][shalf * 16]     = cvt8(h0, h1, smh);
            *(u16x8*)&sAh[srow][shalf * 16 + 8] = cvt8(h2, h3, smh);
        }
        // ---- stage 6 weight tiles (already bf16): 768 units of 8 bf16 ----
        for (int u = t; u < 768; u += 256) {
            int g = u >> 7, rr = (u >> 2) & 31, c = u & 3;
            const unsigned short* wsrc = (g < 3)
                ? (Wih + (size_t)(g * 512 + n0 + rr) * K + k0 + c * 8)
                : (Whh + (size_t)((g - 3) * 512 + n0 + rr) * K + k0 + c * 8);
            *(u16x8*)&sW[g][rr][c * 8] = *(const u16x8*)wsrc;
        }
        __syncthreads();

        // ---- MFMA: A[m=lane&15][k=quad*8+j], B[n=lane&15][k=quad*8+j] (W row-major = B^T) ----
        int ar = wave * 32 + lr;
        bf16x8 ax[2], ah[2], wb[6][2];
        ax[0] = *(const bf16x8*)&sAx[ar][quad * 8];
        ax[1] = *(const bf16x8*)&sAx[ar + 16][quad * 8];
        ah[0] = *(const bf16x8*)&sAh[ar][quad * 8];
        ah[1] = *(const bf16x8*)&sAh[ar + 16][quad * 8];
        #pragma unroll
        for (int g = 0; g < 6; ++g) {
            wb[g][0] = *(const bf16x8*)&sW[g][lr][quad * 8];
            wb[g][1] = *(const bf16x8*)&sW[g][16 + lr][quad * 8];
        }
        #pragma unroll
        for (int g = 0; g < 6; ++g)
            #pragma unroll
            for (int rh = 0; rh < 2; ++rh) {
                bf16x8 af = (g < 3) ? ax[rh] : ah[rh];
                #pragma unroll
                for (int ch = 0; ch < 2; ++ch)
                    acc[g][rh][ch] = __builtin_amdgcn_mfma_f32_16x16x32_bf16(
                        af, wb[g][ch], acc[g][rh][ch], 0, 0, 0);
            }
    }

    // ---- epilogue: GRU gates, C/D layout col=lane&15, row=quad*4+reg ----
    #pragma unroll
    for (int ch = 0; ch < 2; ++ch) {
        int col = n0 + ch * 16 + lr;
        float b_r  = bih[col] + bhh[col];
        float b_z  = bih[H + col] + bhh[H + col];
        float bi_n = bih[2 * H + col];
        float bh_n = bhh[2 * H + col];
        #pragma unroll
        for (int rh = 0; rh < 2; ++rh) {
            #pragma unroll
            for (int reg = 0; reg < 4; ++reg) {
                int row = r0 + wave * 32 + rh * 16 + quad * 4 + reg;
                float ir = acc[0][rh][ch][reg], iz = acc[1][rh][ch][reg], in_ = acc[2][rh][ch][reg];
                float hr = acc[3][rh][ch][reg], hz = acc[4][rh][ch][reg], hn = acc[5][rh][ch][reg];
                float rg = 1.f / (1.f + __expf(-(ir + hr + b_r)));
                float zg = 1.f / (1.f + __expf(-(iz + hz + b_z)));
                float ng = tanhf(in_ + bi_n + rg * (hn + bh_n));
                float ht = mh[row] * h[(size_t)row * H + col];
                out[(size_t)row * H + col] = (1.f - zg) * ng + zg * ht;
            }
        }
    }
}

// ---------------------------------------------------------------------------
// 4) exp-map in place: v *= tanh(0.1*||v||) / (0.1*||v||). one wave per row.
// ---------------------------------------------------------------------------
__global__ void expmap_kernel(float* __restrict__ out, int D) {
    int wave = threadIdx.x >> 6;
    int lane = threadIdx.x & 63;
    int row = blockIdx.x * 4 + wave;
    float4* p = (float4*)(out + (size_t)row * D);
    float4 v0 = p[lane], v1 = p[lane + 64];     // D=512 -> 128 float4/row
    float s = v0.x * v0.x + v0.y * v0.y + v0.z * v0.z + v0.w * v0.w
            + v1.x * v1.x + v1.y * v1.y + v1.z * v1.z + v1.w * v1.w;
    #pragma unroll
    for (int off = 32; off; off >>= 1) s += __shfl_xor(s, off);
    float norm = fmaxf(sqrtf(s), 1e-15f);
    float a = 0.1f * norm;
    float m = tanhf(a) / a;
    v0.x *= m; v0.y *= m; v0.z *= m; v0.w *= m;
    v1.x *= m; v1.y *= m; v1.z *= m; v1.w *= m;
    p[lane] = v0;
    p[lane + 64] = v1;
}

extern "C" void kernel_launch(void* const* d_in, const int* in_sizes, int n_in,
                              void* d_out, int out_size, void* d_ws, size_t ws_size,
                              hipStream_t stream) {
    const float* x   = (const float*)d_in[0];
    const float* h   = (const float*)d_in[1];
    const float* Wih = (const float*)d_in[2];
    const float* Whh = (const float*)d_in[3];
    const float* bih = (const float*)d_in[4];
    const float* bhh = (const float*)d_in[5];
    float* out = (float*)d_out;

    int H = in_sizes[4] / 3;          // 512
    int I = in_sizes[2] / (3 * H);    // 512 (== H == K assumed by the GEMM kernel)
    int B = in_sizes[0] / I;          // 32768

    // workspace: mx[B] f32, mh[B] f32, Wih bf16, Whh bf16  (~3.3 MB)
    float* mx = (float*)d_ws;
    float* mh = mx + B;
    unsigned short* Wih_bf = (unsigned short*)(mh + B);
    unsigned short* Whh_bf = Wih_bf + (size_t)3 * H * I;

    scales_kernel<<<(2 * B) / 4, 256, 0, stream>>>(x, h, mx, mh, B, I);

    int n4i = 3 * H * I / 4;
    cvt_kernel<<<(n4i + 255) / 256, 256, 0, stream>>>(Wih, Wih_bf, n4i);
    int n4h = 3 * H * H / 4;
    cvt_kernel<<<(n4h + 255) / 256, 256, 0, stream>>>(Whh, Whh_bf, n4h);

    dim3 grid(H / 32, B / 128);       // (16, 256): col-block fastest for L2 reuse of A
    gru_gemm_kernel<<<grid, 256, 0, stream>>>(x, h, mx, mh, Wih_bf, Whh_bf, bih, bhh, out, H);

    expmap_kernel<<<B / 4, 256, 0, stream>>>(out, H);
}

// Round 2
// 333.371 us; speedup vs baseline: 1.4579x; 1.4579x over previous
//
#include <hip/hip_runtime.h>
#include <math.h>

// HyperbolicGRUCell: B=32768, I=H=512, c=0.01 (sqrt_c = 0.1)
// R2 pipeline:
//   1) prep_kernel : log-map scale + bf16 cvt of x,h -> ws in chunk order [kc][row]
//   2) wcvt_kernel : W_ih/W_hh fp32 -> bf16 in GEMM staging order [cb][kb][g][q][n]
//   3) gru_gemm    : all staging via global_load_lds(16B); BM=128 BN=64, wave=64x32,
//                    4 merged acc families (r,z merged across the two GEMMs)
//   4) expmap      : in-place exp-map on out

typedef __attribute__((ext_vector_type(8))) short bf16x8;
typedef __attribute__((ext_vector_type(8))) unsigned short u16x8;
typedef __attribute__((ext_vector_type(4))) float f32x4;

__device__ __forceinline__ unsigned short f2bf(float f) {
    unsigned int u = __float_as_uint(f);
    u += 0x7FFFu + ((u >> 16) & 1u);
    return (unsigned short)(u >> 16);
}

__device__ __forceinline__ u16x8 cvt8(float4 v0, float4 v1, float s) {
    u16x8 r;
    r[0] = f2bf(v0.x * s); r[1] = f2bf(v0.y * s); r[2] = f2bf(v0.z * s); r[3] = f2bf(v0.w * s);
    r[4] = f2bf(v1.x * s); r[5] = f2bf(v1.y * s); r[6] = f2bf(v1.z * s); r[7] = f2bf(v1.w * s);
    return r;
}

__device__ __forceinline__ void gload16_lds(const void* g, void* l) {
    __builtin_amdgcn_global_load_lds(
        (const __attribute__((address_space(1))) unsigned int*)g,
        (__attribute__((address_space(3))) unsigned int*)l, 16, 0, 0);
}

__device__ __forceinline__ float sigm(float v) { return 1.f / (1.f + __expf(-v)); }
__device__ __forceinline__ float tanh_fast(float v) { return 1.f - 2.f / (__expf(2.f * v) + 1.f); }

// ---------------------------------------------------------------------------
// 1) prep: per-row log-map multiplier + bf16 cvt, output layout [kc(64)][row(B)]
//    of 16B chunks (8 bf16 each). 32 rows/block, 8 threads/row.
// ---------------------------------------------------------------------------
__global__ void prep_kernel(const float* __restrict__ x, const float* __restrict__ h,
                            u16x8* __restrict__ xt, u16x8* __restrict__ ht,
                            float* __restrict__ mh, int B) {
    int t = threadIdx.x;
    int row = t >> 3, c8 = t & 7;
    int r0 = blockIdx.x * 32;
    bool is_h = (blockIdx.y == 1);
    const float* src = is_h ? h : x;
    const float4* p4 = (const float4*)src + (size_t)(r0 + row) * 128;

    float4 v[8][2];
    float s = 0.f;
    #pragma unroll
    for (int i = 0; i < 8; ++i) {
        int j = i * 16 + c8 * 2;           // lanes c8=0..7 -> 256B contiguous per row
        v[i][0] = p4[j]; v[i][1] = p4[j + 1];
        s += v[i][0].x * v[i][0].x + v[i][0].y * v[i][0].y + v[i][0].z * v[i][0].z + v[i][0].w * v[i][0].w
           + v[i][1].x * v[i][1].x + v[i][1].y * v[i][1].y + v[i][1].z * v[i][1].z + v[i][1].w * v[i][1].w;
    }
    #pragma unroll
    for (int off = 4; off; off >>= 1) s += __shfl_xor(s, off);   // reduce over the 8 lanes of a row
    float norm = fmaxf(sqrtf(s), 1e-15f);
    float a = fminf(0.1f * norm, 1.f - 1e-5f);
    float m = 0.5f * (log1pf(a) - log1pf(-a)) / (0.1f * norm);

    u16x8* dst = is_h ? ht : xt;
    #pragma unroll
    for (int i = 0; i < 8; ++i) {
        int kc = i * 8 + c8;               // chunk-column = col/8
        dst[(size_t)kc * B + r0 + row] = cvt8(v[i][0], v[i][1], m);
    }
    if (is_h && c8 == 0) mh[r0 + row] = m;
}

// ---------------------------------------------------------------------------
// 2) weight cvt+permute into staging order: chunk C = (cb*16+kb)*1536 + g*256 + q*64 + n
//    g 0..2 = Wih{r,z,n}, 3..5 = Whh{r,z,n}; n in [0,64) within col-block cb.
// ---------------------------------------------------------------------------
__global__ void wcvt_kernel(const float* __restrict__ Wih, const float* __restrict__ Whh,
                            u16x8* __restrict__ wst) {
    int C = blockIdx.x * 256 + threadIdx.x;    // 0 .. 196607
    int n  = C & 63;
    int q  = (C >> 6) & 3;
    int t2 = C >> 8;
    int g  = t2 % 6;
    int t3 = t2 / 6;
    int kb = t3 & 15;
    int cb = t3 >> 4;
    const float* src = (g < 3) ? Wih : Whh;
    int grow = (g % 3) * 512 + cb * 64 + n;
    int col0 = kb * 32 + q * 8;
    const float4* p = (const float4*)(src + (size_t)grow * 512 + col0);
    wst[C] = cvt8(p[0], p[1], 1.f);
}

// ---------------------------------------------------------------------------
// 3) fused dual-GEMM + GRU gates. BM=128 BN=64 BK=32, K=512, 4 waves (2m x 2n),
//    wave tile 64x32. All staging via global_load_lds (async, no VGPR roundtrip).
//    LDS chunk map: [0,512)=x [q*128+row], [512,1024)=h, [1024,2560)=W [g*256+q*64+n].
// ---------------------------------------------------------------------------
__launch_bounds__(256, 2)
__global__ void gru_gemm_kernel(const u16x8* __restrict__ xt, const u16x8* __restrict__ ht,
                                const u16x8* __restrict__ wst,
                                const float* __restrict__ h, const float* __restrict__ mh,
                                const float* __restrict__ bih, const float* __restrict__ bhh,
                                float* __restrict__ out, int B) {
    __shared__ u16x8 lds[2560];                 // 40 KB

    int t = threadIdx.x;
    int w = t >> 6, lane = t & 63;
    int quad = lane >> 4, lr = lane & 15;
    int wm = w >> 1, wn = w & 1;
    int cb = blockIdx.x;                        // col-block (64 cols)
    int r0 = blockIdx.y * 128;

    // staging pointers (per lane). A: wave w stages q=w, row-halves 0/1.
    const u16x8* pX0 = xt + (size_t)w * B + r0 + lane;
    const u16x8* pX1 = pX0 + 64;
    const u16x8* pH0 = ht + (size_t)w * B + r0 + lane;
    const u16x8* pH1 = pH0 + 64;
    const u16x8* pW[6];
    #pragma unroll
    for (int jj = 0; jj < 6; ++jj)
        pW[jj] = wst + (size_t)cb * 16 * 1536 + (6 * w + jj) * 64 + lane;

    u16x8* lX0 = lds + w * 128;                 // chunks, wave-uniform bases
    u16x8* lX1 = lX0 + 64;
    u16x8* lH0 = lds + 512 + w * 128;
    u16x8* lH1 = lH0 + 64;
    u16x8* lW[6];
    #pragma unroll
    for (int jj = 0; jj < 6; ++jj) lW[jj] = lds + 1024 + (6 * w + jj) * 64;

    f32x4 aR[4][2], aZ[4][2], aNi[4][2], aNh[4][2];
    #pragma unroll
    for (int rh = 0; rh < 4; ++rh)
        #pragma unroll
        for (int ch = 0; ch < 2; ++ch) {
            aR[rh][ch] = (f32x4){0.f, 0.f, 0.f, 0.f};
            aZ[rh][ch] = (f32x4){0.f, 0.f, 0.f, 0.f};
            aNi[rh][ch] = (f32x4){0.f, 0.f, 0.f, 0.f};
            aNh[rh][ch] = (f32x4){0.f, 0.f, 0.f, 0.f};
        }

    for (int kb = 0; kb < 16; ++kb) {
        __syncthreads();                        // protect LDS from prev iter's readers
        gload16_lds(pX0, lX0); gload16_lds(pX1, lX1);
        gload16_lds(pH0, lH0); gload16_lds(pH1, lH1);
        #pragma unroll
        for (int jj = 0; jj < 6; ++jj) gload16_lds(pW[jj], lW[jj]);
        pX0 += (size_t)4 * B; pX1 += (size_t)4 * B;
        pH0 += (size_t)4 * B; pH1 += (size_t)4 * B;
        #pragma unroll
        for (int jj = 0; jj < 6; ++jj) pW[jj] += 1536;
        __syncthreads();                        // vmcnt drain + barrier -> LDS ready

        bf16x8 ax[4], ah[4], wb[6][2];
        #pragma unroll
        for (int rh = 0; rh < 4; ++rh) {
            int c = quad * 128 + wm * 64 + rh * 16 + lr;
            ax[rh] = *(const bf16x8*)&lds[c];
            ah[rh] = *(const bf16x8*)&lds[512 + c];
        }
        #pragma unroll
        for (int g = 0; g < 6; ++g)
            #pragma unroll
            for (int ch = 0; ch < 2; ++ch)
                wb[g][ch] = *(const bf16x8*)&lds[1024 + g * 256 + quad * 64 + wn * 32 + ch * 16 + lr];

        #pragma unroll
        for (int rh = 0; rh < 4; ++rh)
            #pragma unroll
            for (int ch = 0; ch < 2; ++ch) {
                aR[rh][ch]  = __builtin_amdgcn_mfma_f32_16x16x32_bf16(ax[rh], wb[0][ch], aR[rh][ch], 0, 0, 0);
                aR[rh][ch]  = __builtin_amdgcn_mfma_f32_16x16x32_bf16(ah[rh], wb[3][ch], aR[rh][ch], 0, 0, 0);
                aZ[rh][ch]  = __builtin_amdgcn_mfma_f32_16x16x32_bf16(ax[rh], wb[1][ch], aZ[rh][ch], 0, 0, 0);
                aZ[rh][ch]  = __builtin_amdgcn_mfma_f32_16x16x32_bf16(ah[rh], wb[4][ch], aZ[rh][ch], 0, 0, 0);
                aNi[rh][ch] = __builtin_amdgcn_mfma_f32_16x16x32_bf16(ax[rh], wb[2][ch], aNi[rh][ch], 0, 0, 0);
                aNh[rh][ch] = __builtin_amdgcn_mfma_f32_16x16x32_bf16(ah[rh], wb[5][ch], aNh[rh][ch], 0, 0, 0);
            }
    }

    // epilogue: C/D layout col=lane&15, row=quad*4+reg
    #pragma unroll
    for (int ch = 0; ch < 2; ++ch) {
        int col = cb * 64 + wn * 32 + ch * 16 + lr;
        float br  = bih[col] + bhh[col];
        float bz  = bih[512 + col] + bhh[512 + col];
        float bin = bih[1024 + col];
        float bhn = bhh[1024 + col];
        #pragma unroll
        for (int rh = 0; rh < 4; ++rh)
            #pragma unroll
            for (int reg = 0; reg < 4; ++reg) {
                int row = r0 + wm * 64 + rh * 16 + quad * 4 + reg;
                float rg = sigm(aR[rh][ch][reg] + br);
                float zg = sigm(aZ[rh][ch][reg] + bz);
                float ng = tanh_fast(aNi[rh][ch][reg] + bin + rg * (aNh[rh][ch][reg] + bhn));
                float ht_ = mh[row] * h[(size_t)row * 512 + col];
                out[(size_t)row * 512 + col] = (1.f - zg) * ng + zg * ht_;
            }
    }
}

// ---------------------------------------------------------------------------
// 4) exp-map in place: v *= tanh(0.1*||v||) / (0.1*||v||). one wave per row.
// ---------------------------------------------------------------------------
__global__ void expmap_kernel(float* __restrict__ out, int D) {
    int wave = threadIdx.x >> 6;
    int lane = threadIdx.x & 63;
    int row = blockIdx.x * 4 + wave;
    float4* p = (float4*)(out + (size_t)row * D);
    float4 v0 = p[lane], v1 = p[lane + 64];
    float s = v0.x * v0.x + v0.y * v0.y + v0.z * v0.z + v0.w * v0.w
            + v1.x * v1.x + v1.y * v1.y + v1.z * v1.z + v1.w * v1.w;
    #pragma unroll
    for (int off = 32; off; off >>= 1) s += __shfl_xor(s, off);
    float norm = fmaxf(sqrtf(s), 1e-15f);
    float a = 0.1f * norm;
    float m = tanhf(a) / a;
    v0.x *= m; v0.y *= m; v0.z *= m; v0.w *= m;
    v1.x *= m; v1.y *= m; v1.z *= m; v1.w *= m;
    p[lane] = v0;
    p[lane + 64] = v1;
}

extern "C" void kernel_launch(void* const* d_in, const int* in_sizes, int n_in,
                              void* d_out, int out_size, void* d_ws, size_t ws_size,
                              hipStream_t stream) {
    const float* x   = (const float*)d_in[0];
    const float* h   = (const float*)d_in[1];
    const float* Wih = (const float*)d_in[2];
    const float* Whh = (const float*)d_in[3];
    const float* bih = (const float*)d_in[4];
    const float* bhh = (const float*)d_in[5];
    float* out = (float*)d_out;

    int H = in_sizes[4] / 3;          // 512
    int I = in_sizes[2] / (3 * H);    // 512
    int B = in_sizes[0] / I;          // 32768

    // ws: xt chunks (64*B), ht chunks (64*B), W staged (196608 chunks), mh (B f32) ~ 70.4 MB
    u16x8* xt  = (u16x8*)d_ws;
    u16x8* ht  = xt + (size_t)64 * B;
    u16x8* wst = ht + (size_t)64 * B;
    float* mh  = (float*)(wst + 196608);

    prep_kernel<<<dim3(B / 32, 2), 256, 0, stream>>>(x, h, xt, ht, mh, B);
    wcvt_kernel<<<768, 256, 0, stream>>>(Wih, Whh, wst);
    gru_gemm_kernel<<<dim3(8, B / 128), 256, 0, stream>>>(xt, ht, wst, h, mh, bih, bhh, out, B);
    expmap_kernel<<<B / 4, 256, 0, stream>>>(out, H);
}

// Round 3
// 333.264 us; speedup vs baseline: 1.4584x; 1.0003x over previous
//
#include <hip/hip_runtime.h>
#include <math.h>

// HyperbolicGRUCell: B=32768, I=H=512, c=0.01 (sqrt_c = 0.1)
// R3:
//   1) prep_kernel : log-map + bf16 cvt; LDS transpose so ws writes are coalesced
//   2) wcvt_kernel : W fp32 -> bf16 in staging order [cb][kb][g][q][n]
//   3) gru_gemm    : BK=64, W via global_load_lds->48KB LDS, A DIRECT global->VGPR
//                    (coalesced fragment loads from [kc][row] layout, issued before
//                    the barriers so their latency hides under the W drain)
//   4) expmap      : in-place exp-map on out

typedef __attribute__((ext_vector_type(8))) short bf16x8;
typedef __attribute__((ext_vector_type(8))) unsigned short u16x8;
typedef __attribute__((ext_vector_type(4))) float f32x4;

__device__ __forceinline__ unsigned short f2bf(float f) {
    unsigned int u = __float_as_uint(f);
    u += 0x7FFFu + ((u >> 16) & 1u);
    return (unsigned short)(u >> 16);
}

__device__ __forceinline__ u16x8 cvt8(float4 v0, float4 v1, float s) {
    u16x8 r;
    r[0] = f2bf(v0.x * s); r[1] = f2bf(v0.y * s); r[2] = f2bf(v0.z * s); r[3] = f2bf(v0.w * s);
    r[4] = f2bf(v1.x * s); r[5] = f2bf(v1.y * s); r[6] = f2bf(v1.z * s); r[7] = f2bf(v1.w * s);
    return r;
}

__device__ __forceinline__ void gload16_lds(const void* g, void* l) {
    __builtin_amdgcn_global_load_lds(
        (const __attribute__((address_space(1))) unsigned int*)g,
        (__attribute__((address_space(3))) unsigned int*)l, 16, 0, 0);
}

__device__ __forceinline__ float sigm(float v) { return 1.f / (1.f + __expf(-v)); }
__device__ __forceinline__ float tanh_fast(float v) { return 1.f - 2.f / (__expf(2.f * v) + 1.f); }

// ---------------------------------------------------------------------------
// 1) prep: 32 rows/block, 8 lanes/row. Reads coalesced (256B runs), norms via
//    shuffle, bf16 chunks staged to LDS (stride 65), then written out so that
//    32 consecutive lanes write 32 consecutive rows of one chunk-col (512B runs).
// ---------------------------------------------------------------------------
__global__ void prep_kernel(const float* __restrict__ x, const float* __restrict__ h,
                            u16x8* __restrict__ xt, u16x8* __restrict__ ht,
                            float* __restrict__ mh, int B) {
    __shared__ u16x8 lbuf[32 * 65];
    int t = threadIdx.x;
    int row = t >> 3, c8 = t & 7;
    int r0 = blockIdx.x * 32;
    bool is_h = (blockIdx.y == 1);
    const float* src = is_h ? h : x;
    const float4* p4 = (const float4*)src + (size_t)(r0 + row) * 128;

    float4 v[8][2];
    float s = 0.f;
    #pragma unroll
    for (int i = 0; i < 8; ++i) {
        int j = i * 16 + c8 * 2;
        v[i][0] = p4[j]; v[i][1] = p4[j + 1];
        s += v[i][0].x * v[i][0].x + v[i][0].y * v[i][0].y + v[i][0].z * v[i][0].z + v[i][0].w * v[i][0].w
           + v[i][1].x * v[i][1].x + v[i][1].y * v[i][1].y + v[i][1].z * v[i][1].z + v[i][1].w * v[i][1].w;
    }
    #pragma unroll
    for (int off = 4; off; off >>= 1) s += __shfl_xor(s, off);
    float norm = fmaxf(sqrtf(s), 1e-15f);
    float a = fminf(0.1f * norm, 1.f - 1e-5f);
    float m = 0.5f * (log1pf(a) - log1pf(-a)) / (0.1f * norm);

    #pragma unroll
    for (int i = 0; i < 8; ++i)
        lbuf[row * 65 + i * 8 + c8] = cvt8(v[i][0], v[i][1], m);
    if (is_h && c8 == 0) mh[r0 + row] = m;
    __syncthreads();

    u16x8* dst = is_h ? ht : xt;
    #pragma unroll
    for (int it = 0; it < 8; ++it) {
        int u = it * 256 + t;
        int rr = u & 31, kc = u >> 5;
        dst[(size_t)kc * B + r0 + rr] = lbuf[rr * 65 + kc];
    }
}

// ---------------------------------------------------------------------------
// 2) weight cvt+permute: chunk C = (cb*16+kb)*1536 + g*256 + q*64 + n
// ---------------------------------------------------------------------------
__global__ void wcvt_kernel(const float* __restrict__ Wih, const float* __restrict__ Whh,
                            u16x8* __restrict__ wst) {
    int C = blockIdx.x * 256 + threadIdx.x;
    int n  = C & 63;
    int q  = (C >> 6) & 3;
    int t2 = C >> 8;
    int g  = t2 % 6;
    int t3 = t2 / 6;
    int kb = t3 & 15;
    int cb = t3 >> 4;
    const float* src = (g < 3) ? Wih : Whh;
    int grow = (g % 3) * 512 + cb * 64 + n;
    int col0 = kb * 32 + q * 8;
    const float4* p = (const float4*)(src + (size_t)grow * 512 + col0);
    wst[C] = cvt8(p[0], p[1], 1.f);
}

// ---------------------------------------------------------------------------
// 3) fused dual-GEMM + GRU. BM=128 BN=64 BK=64 (8 outer iters), 4 waves,
//    wave tile 64x32, 4 merged acc families. A fragments loaded straight from
//    global (coalesced from [kc][row] layout); only W goes through LDS.
// ---------------------------------------------------------------------------
__launch_bounds__(256, 2)
__global__ void gru_gemm_kernel(const u16x8* __restrict__ xt, const u16x8* __restrict__ ht,
                                const u16x8* __restrict__ wst,
                                const float* __restrict__ h, const float* __restrict__ mh,
                                const float* __restrict__ bih, const float* __restrict__ bhh,
                                float* __restrict__ out, int B) {
    __shared__ u16x8 lds[3072];                 // 48 KB: [half(2)][g(6)][q(4)][n(64)]

    int t = threadIdx.x;
    int w = t >> 6, lane = t & 63;
    int quad = lane >> 4, lr = lane & 15;
    int wm = w >> 1, wn = w & 1;
    int cb = blockIdx.x;
    int r0 = blockIdx.y * 128;

    // A fragment pointers: chunk = kc*B + row; lanes (quad,lr) -> 4 x 256B segments
    const u16x8* pX0 = xt + (size_t)quad * B + r0 + wm * 64 + lr;   // kb = 8*it
    const u16x8* pX1 = pX0 + (size_t)4 * B;                          // kb = 8*it+4
    const u16x8* pH0 = ht + (size_t)quad * B + r0 + wm * 64 + lr;
    const u16x8* pH1 = pH0 + (size_t)4 * B;
    // W staging: wave w stages chunks (6w+jj)*64+lane for both halves
    const u16x8* pW = wst + (size_t)cb * 24576 + w * 384 + lane;
    u16x8* lW = lds + w * 384;                  // wave-uniform base

    f32x4 aR[4][2], aZ[4][2], aNi[4][2], aNh[4][2];
    #pragma unroll
    for (int rh = 0; rh < 4; ++rh)
        #pragma unroll
        for (int ch = 0; ch < 2; ++ch) {
            aR[rh][ch]  = (f32x4){0.f, 0.f, 0.f, 0.f};
            aZ[rh][ch]  = (f32x4){0.f, 0.f, 0.f, 0.f};
            aNi[rh][ch] = (f32x4){0.f, 0.f, 0.f, 0.f};
            aNh[rh][ch] = (f32x4){0.f, 0.f, 0.f, 0.f};
        }

    for (int it = 0; it < 8; ++it) {
        // ---- A fragment loads for both K-halves: issue BEFORE the barriers so
        //      global latency overlaps the W staging drain ----
        bf16x8 ax[2][4], ah[2][4];
        #pragma unroll
        for (int rh = 0; rh < 4; ++rh) {
            ax[0][rh] = *(const bf16x8*)(pX0 + rh * 16);
            ax[1][rh] = *(const bf16x8*)(pX1 + rh * 16);
            ah[0][rh] = *(const bf16x8*)(pH0 + rh * 16);
            ah[1][rh] = *(const bf16x8*)(pH1 + rh * 16);
        }
        pX0 += (size_t)8 * B; pX1 += (size_t)8 * B;
        pH0 += (size_t)8 * B; pH1 += (size_t)8 * B;

        __syncthreads();                        // prev iter's W readers done
        #pragma unroll
        for (int jj = 0; jj < 6; ++jj) {
            gload16_lds(pW + jj * 64,        lW + jj * 64);          // half 0
            gload16_lds(pW + 1536 + jj * 64, lW + 1536 + jj * 64);   // half 1
        }
        pW += 3072;
        __syncthreads();                        // W (and A) in place

        #pragma unroll
        for (int h2 = 0; h2 < 2; ++h2) {
            bf16x8 wb[6][2];
            #pragma unroll
            for (int g = 0; g < 6; ++g)
                #pragma unroll
                for (int ch = 0; ch < 2; ++ch)
                    wb[g][ch] = *(const bf16x8*)&lds[h2 * 1536 + g * 256 + quad * 64 + wn * 32 + ch * 16 + lr];
            #pragma unroll
            for (int rh = 0; rh < 4; ++rh)
                #pragma unroll
                for (int ch = 0; ch < 2; ++ch) {
                    aR[rh][ch]  = __builtin_amdgcn_mfma_f32_16x16x32_bf16(ax[h2][rh], wb[0][ch], aR[rh][ch], 0, 0, 0);
                    aR[rh][ch]  = __builtin_amdgcn_mfma_f32_16x16x32_bf16(ah[h2][rh], wb[3][ch], aR[rh][ch], 0, 0, 0);
                    aZ[rh][ch]  = __builtin_amdgcn_mfma_f32_16x16x32_bf16(ax[h2][rh], wb[1][ch], aZ[rh][ch], 0, 0, 0);
                    aZ[rh][ch]  = __builtin_amdgcn_mfma_f32_16x16x32_bf16(ah[h2][rh], wb[4][ch], aZ[rh][ch], 0, 0, 0);
                    aNi[rh][ch] = __builtin_amdgcn_mfma_f32_16x16x32_bf16(ax[h2][rh], wb[2][ch], aNi[rh][ch], 0, 0, 0);
                    aNh[rh][ch] = __builtin_amdgcn_mfma_f32_16x16x32_bf16(ah[h2][rh], wb[5][ch], aNh[rh][ch], 0, 0, 0);
                }
        }
    }

    // epilogue: C/D layout col=lane&15, row=quad*4+reg
    #pragma unroll
    for (int ch = 0; ch < 2; ++ch) {
        int col = cb * 64 + wn * 32 + ch * 16 + lr;
        float br  = bih[col] + bhh[col];
        float bz  = bih[512 + col] + bhh[512 + col];
        float bin = bih[1024 + col];
        float bhn = bhh[1024 + col];
        #pragma unroll
        for (int rh = 0; rh < 4; ++rh)
            #pragma unroll
            for (int reg = 0; reg < 4; ++reg) {
                int row = r0 + wm * 64 + rh * 16 + quad * 4 + reg;
                float rg = sigm(aR[rh][ch][reg] + br);
                float zg = sigm(aZ[rh][ch][reg] + bz);
                float ng = tanh_fast(aNi[rh][ch][reg] + bin + rg * (aNh[rh][ch][reg] + bhn));
                float ht_ = mh[row] * h[(size_t)row * 512 + col];
                out[(size_t)row * 512 + col] = (1.f - zg) * ng + zg * ht_;
            }
    }
}

// ---------------------------------------------------------------------------
// 4) exp-map in place
// ---------------------------------------------------------------------------
__global__ void expmap_kernel(float* __restrict__ out, int D) {
    int wave = threadIdx.x >> 6;
    int lane = threadIdx.x & 63;
    int row = blockIdx.x * 4 + wave;
    float4* p = (float4*)(out + (size_t)row * D);
    float4 v0 = p[lane], v1 = p[lane + 64];
    float s = v0.x * v0.x + v0.y * v0.y + v0.z * v0.z + v0.w * v0.w
            + v1.x * v1.x + v1.y * v1.y + v1.z * v1.z + v1.w * v1.w;
    #pragma unroll
    for (int off = 32; off; off >>= 1) s += __shfl_xor(s, off);
    float norm = fmaxf(sqrtf(s), 1e-15f);
    float a = 0.1f * norm;
    float m = tanhf(a) / a;
    v0.x *= m; v0.y *= m; v0.z *= m; v0.w *= m;
    v1.x *= m; v1.y *= m; v1.z *= m; v1.w *= m;
    p[lane] = v0;
    p[lane + 64] = v1;
}

extern "C" void kernel_launch(void* const* d_in, const int* in_sizes, int n_in,
                              void* d_out, int out_size, void* d_ws, size_t ws_size,
                              hipStream_t stream) {
    const float* x   = (const float*)d_in[0];
    const float* h   = (const float*)d_in[1];
    const float* Wih = (const float*)d_in[2];
    const float* Whh = (const float*)d_in[3];
    const float* bih = (const float*)d_in[4];
    const float* bhh = (const float*)d_in[5];
    float* out = (float*)d_out;

    int H = in_sizes[4] / 3;          // 512
    int I = in_sizes[2] / (3 * H);    // 512
    int B = in_sizes[0] / I;          // 32768

    u16x8* xt  = (u16x8*)d_ws;
    u16x8* ht  = xt + (size_t)64 * B;
    u16x8* wst = ht + (size_t)64 * B;
    float* mh  = (float*)(wst + 196608);

    prep_kernel<<<dim3(B / 32, 2), 256, 0, stream>>>(x, h, xt, ht, mh, B);
    wcvt_kernel<<<768, 256, 0, stream>>>(Wih, Whh, wst);
    gru_gemm_kernel<<<dim3(8, B / 128), 256, 0, stream>>>(xt, ht, wst, h, mh, bih, bhh, out, B);
    expmap_kernel<<<B / 4, 256, 0, stream>>>(out, H);
}

// Round 5
// 322.191 us; speedup vs baseline: 1.5085x; 1.0344x over previous
//
#include <hip/hip_runtime.h>
#include <math.h>

// HyperbolicGRUCell: B=32768, I=H=512, c=0.01 (sqrt_c = 0.1)
// R5: R4's double-buffered K-loop with EXPLICIT pipeline sync:
//     s_waitcnt vmcnt(0) (drains only last iter's prefetch, issued a full MFMA
//     block earlier) + raw s_barrier. __syncthreads() was not draining the
//     global_load_lds DMA writes -> R4 raced; this makes the drain explicit
//     while keeping it off the critical path.
//   1) prep_kernel : log-map + bf16 cvt -> ws chunks [kc][row]
//   2) wcvt_kernel : W fp32 -> bf16 in staging order [cb][kb][g][q][n]
//   3) gru_gemm    : BM=128 BN=64 BK=32, 80KB LDS double buffer, 4 merged acc
//   4) expmap      : in-place exp-map on out

typedef __attribute__((ext_vector_type(8))) short bf16x8;
typedef __attribute__((ext_vector_type(8))) unsigned short u16x8;
typedef __attribute__((ext_vector_type(4))) float f32x4;

__device__ __forceinline__ unsigned short f2bf(float f) {
    unsigned int u = __float_as_uint(f);
    u += 0x7FFFu + ((u >> 16) & 1u);
    return (unsigned short)(u >> 16);
}

__device__ __forceinline__ u16x8 cvt8(float4 v0, float4 v1, float s) {
    u16x8 r;
    r[0] = f2bf(v0.x * s); r[1] = f2bf(v0.y * s); r[2] = f2bf(v0.z * s); r[3] = f2bf(v0.w * s);
    r[4] = f2bf(v1.x * s); r[5] = f2bf(v1.y * s); r[6] = f2bf(v1.z * s); r[7] = f2bf(v1.w * s);
    return r;
}

__device__ __forceinline__ void gload16_lds(const void* g, void* l) {
    __builtin_amdgcn_global_load_lds(
        (const __attribute__((address_space(1))) unsigned int*)g,
        (__attribute__((address_space(3))) unsigned int*)l, 16, 0, 0);
}

// drain all outstanding VMEM (incl. global_load_lds DMA) then raw barrier.
__device__ __forceinline__ void pipeline_barrier() {
    asm volatile("s_waitcnt vmcnt(0)" ::: "memory");
    __builtin_amdgcn_s_barrier();
    asm volatile("" ::: "memory");
}

__device__ __forceinline__ float sigm(float v) { return 1.f / (1.f + __expf(-v)); }
__device__ __forceinline__ float tanh_fast(float v) { return 1.f - 2.f / (__expf(2.f * v) + 1.f); }

// ---------------------------------------------------------------------------
// 1) prep: 32 rows/block, 8 lanes/row; coalesced reads, LDS transpose so the
//    [kc][row] chunk writes are 512B-contiguous runs.
// ---------------------------------------------------------------------------
__global__ void prep_kernel(const float* __restrict__ x, const float* __restrict__ h,
                            u16x8* __restrict__ xt, u16x8* __restrict__ ht,
                            float* __restrict__ mh, int B) {
    __shared__ u16x8 lbuf[32 * 65];
    int t = threadIdx.x;
    int row = t >> 3, c8 = t & 7;
    int r0 = blockIdx.x * 32;
    bool is_h = (blockIdx.y == 1);
    const float* src = is_h ? h : x;
    const float4* p4 = (const float4*)src + (size_t)(r0 + row) * 128;

    float4 v[8][2];
    float s = 0.f;
    #pragma unroll
    for (int i = 0; i < 8; ++i) {
        int j = i * 16 + c8 * 2;
        v[i][0] = p4[j]; v[i][1] = p4[j + 1];
        s += v[i][0].x * v[i][0].x + v[i][0].y * v[i][0].y + v[i][0].z * v[i][0].z + v[i][0].w * v[i][0].w
           + v[i][1].x * v[i][1].x + v[i][1].y * v[i][1].y + v[i][1].z * v[i][1].z + v[i][1].w * v[i][1].w;
    }
    #pragma unroll
    for (int off = 4; off; off >>= 1) s += __shfl_xor(s, off);
    float norm = fmaxf(sqrtf(s), 1e-15f);
    float a = fminf(0.1f * norm, 1.f - 1e-5f);
    float m = 0.5f * (log1pf(a) - log1pf(-a)) / (0.1f * norm);

    #pragma unroll
    for (int i = 0; i < 8; ++i)
        lbuf[row * 65 + i * 8 + c8] = cvt8(v[i][0], v[i][1], m);
    if (is_h && c8 == 0) mh[r0 + row] = m;
    __syncthreads();

    u16x8* dst = is_h ? ht : xt;
    #pragma unroll
    for (int it = 0; it < 8; ++it) {
        int u = it * 256 + t;
        int rr = u & 31, kc = u >> 5;
        dst[(size_t)kc * B + r0 + rr] = lbuf[rr * 65 + kc];
    }
}

// ---------------------------------------------------------------------------
// 2) weight cvt+permute: chunk C = (cb*16+kb)*1536 + g*256 + q*64 + n
// ---------------------------------------------------------------------------
__global__ void wcvt_kernel(const float* __restrict__ Wih, const float* __restrict__ Whh,
                            u16x8* __restrict__ wst) {
    int C = blockIdx.x * 256 + threadIdx.x;
    int n  = C & 63;
    int q  = (C >> 6) & 3;
    int t2 = C >> 8;
    int g  = t2 % 6;
    int t3 = t2 / 6;
    int kb = t3 & 15;
    int cb = t3 >> 4;
    const float* src = (g < 3) ? Wih : Whh;
    int grow = (g % 3) * 512 + cb * 64 + n;
    int col0 = kb * 32 + q * 8;
    const float4* p = (const float4*)(src + (size_t)grow * 512 + col0);
    wst[C] = cvt8(p[0], p[1], 1.f);
}

// ---------------------------------------------------------------------------
// 3) fused dual-GEMM + GRU. BM=128 BN=64 BK=32 (16 iters), 4 waves 2m x 2n,
//    wave tile 64x32, 4 merged acc families (128 AGPR).
//    80 KB LDS: buf p at p*2560 chunks; within buf:
//      [0,512)    x-A chunks  [q(4)][row(128)]
//      [512,1024) h-A chunks
//      [1024,2560) W chunks   [g(6)][q(4)][n(64)]
//    Per iter: vmcnt(0)+barrier; prefetch(kb+1)->buf[p^1]; ds_read+MFMA buf[p].
// ---------------------------------------------------------------------------
__launch_bounds__(256, 2)
__global__ void gru_gemm_kernel(const u16x8* __restrict__ xt, const u16x8* __restrict__ ht,
                                const u16x8* __restrict__ wst,
                                const float* __restrict__ h, const float* __restrict__ mh,
                                const float* __restrict__ bih, const float* __restrict__ bhh,
                                float* __restrict__ out, int B) {
    __shared__ u16x8 lds[5120];                 // 80 KB

    int t = threadIdx.x;
    int w = t >> 6, lane = t & 63;
    int quad = lane >> 4, lr = lane & 15;
    int wm = w >> 1, wn = w & 1;
    int r0 = blockIdx.x * 128;                  // row-group fastest
    int cb = blockIdx.y;

    // staging sources (per lane): wave w stages A mat = w>>1 (0=x,1=h), q-pair (w&1)*2
    const u16x8* aBase = (w & 2) ? ht : xt;
    const u16x8* pa0 = aBase + (size_t)((w & 1) * 2) * B + r0 + lane;
    const u16x8* pa1 = pa0 + (size_t)B;
    const u16x8* pw  = wst + (size_t)cb * 24576 + w * 384 + lane;
    u16x8* dA = lds + w * 256;
    u16x8* dW = lds + 1024 + w * 384;

    f32x4 aR[4][2], aZ[4][2], aNi[4][2], aNh[4][2];
    #pragma unroll
    for (int rh = 0; rh < 4; ++rh)
        #pragma unroll
        for (int ch = 0; ch < 2; ++ch) {
            aR[rh][ch]  = (f32x4){0.f, 0.f, 0.f, 0.f};
            aZ[rh][ch]  = (f32x4){0.f, 0.f, 0.f, 0.f};
            aNi[rh][ch] = (f32x4){0.f, 0.f, 0.f, 0.f};
            aNh[rh][ch] = (f32x4){0.f, 0.f, 0.f, 0.f};
        }

    // prologue: stage kb=0 into buf 0
    gload16_lds(pa0,       dA);
    gload16_lds(pa0 + 64,  dA + 64);
    gload16_lds(pa1,       dA + 128);
    gload16_lds(pa1 + 64,  dA + 192);
    #pragma unroll
    for (int j = 0; j < 6; ++j) gload16_lds(pw + j * 64, dW + j * 64);

    int p = 0;
    for (int kb = 0; kb < 16; ++kb) {
        pipeline_barrier();     // drains prefetch(kb) (issued one MFMA block ago)
        if (kb < 15) {
            const u16x8* qa0 = pa0 + (size_t)(kb + 1) * 4 * B;
            const u16x8* qa1 = pa1 + (size_t)(kb + 1) * 4 * B;
            const u16x8* qw  = pw  + (size_t)(kb + 1) * 1536;
            u16x8* eA = lds + (p ^ 1) * 2560 + w * 256;
            u16x8* eW = lds + (p ^ 1) * 2560 + 1024 + w * 384;
            gload16_lds(qa0,      eA);
            gload16_lds(qa0 + 64, eA + 64);
            gload16_lds(qa1,      eA + 128);
            gload16_lds(qa1 + 64, eA + 192);
            #pragma unroll
            for (int j = 0; j < 6; ++j) gload16_lds(qw + j * 64, eW + j * 64);
        }

        const u16x8* bp = lds + p * 2560;
        bf16x8 ax[4], ah[4], wb[6][2];
        #pragma unroll
        for (int rh = 0; rh < 4; ++rh) {
            int c = quad * 128 + wm * 64 + rh * 16 + lr;
            ax[rh] = *(const bf16x8*)&bp[c];
            ah[rh] = *(const bf16x8*)&bp[512 + c];
        }
        #pragma unroll
        for (int g = 0; g < 6; ++g) {
            int c = 1024 + g * 256 + quad * 64 + wn * 32 + lr;
            wb[g][0] = *(const bf16x8*)&bp[c];
            wb[g][1] = *(const bf16x8*)&bp[c + 16];
        }
        #pragma unroll
        for (int rh = 0; rh < 4; ++rh)
            #pragma unroll
            for (int ch = 0; ch < 2; ++ch) {
                aR[rh][ch]  = __builtin_amdgcn_mfma_f32_16x16x32_bf16(ax[rh], wb[0][ch], aR[rh][ch], 0, 0, 0);
                aR[rh][ch]  = __builtin_amdgcn_mfma_f32_16x16x32_bf16(ah[rh], wb[3][ch], aR[rh][ch], 0, 0, 0);
                aZ[rh][ch]  = __builtin_amdgcn_mfma_f32_16x16x32_bf16(ax[rh], wb[1][ch], aZ[rh][ch], 0, 0, 0);
                aZ[rh][ch]  = __builtin_amdgcn_mfma_f32_16x16x32_bf16(ah[rh], wb[4][ch], aZ[rh][ch], 0, 0, 0);
                aNi[rh][ch] = __builtin_amdgcn_mfma_f32_16x16x32_bf16(ax[rh], wb[2][ch], aNi[rh][ch], 0, 0, 0);
                aNh[rh][ch] = __builtin_amdgcn_mfma_f32_16x16x32_bf16(ah[rh], wb[5][ch], aNh[rh][ch], 0, 0, 0);
            }
        p ^= 1;
    }

    // epilogue: C/D layout col=lane&15, row=quad*4+reg
    #pragma unroll
    for (int ch = 0; ch < 2; ++ch) {
        int col = cb * 64 + wn * 32 + ch * 16 + lr;
        float br  = bih[col] + bhh[col];
        float bz  = bih[512 + col] + bhh[512 + col];
        float bin = bih[1024 + col];
        float bhn = bhh[1024 + col];
        #pragma unroll
        for (int rh = 0; rh < 4; ++rh)
            #pragma unroll
            for (int reg = 0; reg < 4; ++reg) {
                int row = r0 + wm * 64 + rh * 16 + quad * 4 + reg;
                float rg = sigm(aR[rh][ch][reg] + br);
                float zg = sigm(aZ[rh][ch][reg] + bz);
                float ng = tanh_fast(aNi[rh][ch][reg] + bin + rg * (aNh[rh][ch][reg] + bhn));
                float ht_ = mh[row] * h[(size_t)row * 512 + col];
                out[(size_t)row * 512 + col] = (1.f - zg) * ng + zg * ht_;
            }
    }
}

// ---------------------------------------------------------------------------
// 4) exp-map in place
// ---------------------------------------------------------------------------
__global__ void expmap_kernel(float* __restrict__ out, int D) {
    int wave = threadIdx.x >> 6;
    int lane = threadIdx.x & 63;
    int row = blockIdx.x * 4 + wave;
    float4* p = (float4*)(out + (size_t)row * D);
    float4 v0 = p[lane], v1 = p[lane + 64];
    float s = v0.x * v0.x + v0.y * v0.y + v0.z * v0.z + v0.w * v0.w
            + v1.x * v1.x + v1.y * v1.y + v1.z * v1.z + v1.w * v1.w;
    #pragma unroll
    for (int off = 32; off; off >>= 1) s += __shfl_xor(s, off);
    float norm = fmaxf(sqrtf(s), 1e-15f);
    float a = 0.1f * norm;
    float m = tanhf(a) / a;
    v0.x *= m; v0.y *= m; v0.z *= m; v0.w *= m;
    v1.x *= m; v1.y *= m; v1.z *= m; v1.w *= m;
    p[lane] = v0;
    p[lane + 64] = v1;
}

extern "C" void kernel_launch(void* const* d_in, const int* in_sizes, int n_in,
                              void* d_out, int out_size, void* d_ws, size_t ws_size,
                              hipStream_t stream) {
    const float* x   = (const float*)d_in[0];
    const float* h   = (const float*)d_in[1];
    const float* Wih = (const float*)d_in[2];
    const float* Whh = (const float*)d_in[3];
    const float* bih = (const float*)d_in[4];
    const float* bhh = (const float*)d_in[5];
    float* out = (float*)d_out;

    int H = in_sizes[4] / 3;          // 512
    int I = in_sizes[2] / (3 * H);    // 512
    int B = in_sizes[0] / I;          // 32768

    u16x8* xt  = (u16x8*)d_ws;
    u16x8* ht  = xt + (size_t)64 * B;
    u16x8* wst = ht + (size_t)64 * B;
    float* mh  = (float*)(wst + 196608);

    prep_kernel<<<dim3(B / 32, 2), 256, 0, stream>>>(x, h, xt, ht, mh, B);
    wcvt_kernel<<<768, 256, 0, stream>>>(Wih, Whh, wst);
    gru_gemm_kernel<<<dim3(B / 128, 8), 256, 0, stream>>>(xt, ht, wst, h, mh, bih, bhh, out, B);
    expmap_kernel<<<B / 4, 256, 0, stream>>>(out, H);
}